// Round 7
// baseline (659.706 us; speedup 1.0000x reference)
//
#include <hip/hip_runtime.h>
#include <hip/hip_bf16.h>

#define N_NODES  50000
#define N_GRAPHS 128
#define N_EDGES  800000
#define HID      128
#define SCAN_BS  256
#define SCAN_NB  ((N_NODES + SCAN_BS - 1) / SCAN_BS)

typedef __attribute__((ext_vector_type(8))) short short8;
typedef __attribute__((ext_vector_type(4))) float f32x4;

static __device__ __forceinline__ ushort f2bf(float f){
  __hip_bfloat16 h = __float2bfloat16(f);
  return *reinterpret_cast<ushort*>(&h);
}
static __device__ __forceinline__ float bf_lo(uint pk){ return __uint_as_float(pk << 16); }
static __device__ __forceinline__ float bf_hi(uint pk){ return __uint_as_float(pk & 0xffff0000u); }

// ---------------- graph preprocessing ----------------

__global__ void k_count(const int* __restrict__ dst, int* __restrict__ deg, int E){
  int i = blockIdx.x*blockDim.x + threadIdx.x;
  if (i < E) atomicAdd(&deg[dst[i]], 1);
}

__global__ void k_dinv(const int* __restrict__ deg, float* __restrict__ dinv, int N){
  int i = blockIdx.x*blockDim.x + threadIdx.x;
  if (i < N) dinv[i] = rsqrtf((float)(deg[i] + 1));   // +1 self loop
}

__global__ void k_scan1(const int* __restrict__ deg, int* __restrict__ lexc,
                        int* __restrict__ bsum, int N){
  __shared__ int s[SCAN_BS];
  int t = threadIdx.x, i = blockIdx.x*SCAN_BS + t;
  int v = (i < N) ? deg[i] : 0;
  s[t] = v;
  __syncthreads();
  int acc = v;
  for (int d = 1; d < SCAN_BS; d <<= 1){
    int u = (t >= d) ? s[t-d] : 0;
    __syncthreads();
    acc += u; s[t] = acc;
    __syncthreads();
  }
  if (i < N) lexc[i] = acc - v;
  if (t == SCAN_BS-1) bsum[blockIdx.x] = acc;
}

__global__ void k_scan2(const int* __restrict__ bsum, int* __restrict__ boff,
                        int* __restrict__ row_start){
  __shared__ int s[SCAN_NB];
  int t = threadIdx.x;
  int v = (t < SCAN_NB) ? bsum[t] : 0;
  if (t < SCAN_NB) s[t] = v;
  __syncthreads();
  int acc = v;
  for (int d = 1; d < SCAN_NB; d <<= 1){
    int u = (t >= d && t - d < SCAN_NB) ? s[t-d] : 0;
    __syncthreads();
    if (t < SCAN_NB){ acc += u; s[t] = acc; }
    __syncthreads();
  }
  if (t < SCAN_NB) boff[t] = acc - v;
  if (t == SCAN_NB-1) row_start[N_NODES] = acc;
}

__global__ void k_scan3(const int* __restrict__ lexc, const int* __restrict__ boff,
                        int* __restrict__ row_start, int N){
  int i = blockIdx.x*blockDim.x + threadIdx.x;
  if (i < N) row_start[i] = lexc[i] + boff[i >> 8];
}

__global__ void k_scatter(const int* __restrict__ src, const int* __restrict__ dst,
                          const int* __restrict__ row_start, int* __restrict__ cursor,
                          int* __restrict__ csr_src, int E){
  int i = blockIdx.x*blockDim.x + threadIdx.x;
  if (i >= E) return;
  int d = dst[i];
  int pos = row_start[d] + atomicAdd(&cursor[d], 1);
  csr_src[pos] = src[i];
}

// transpose + bf16-convert weight: W[K][N] -> Wt[N][K]
__global__ void k_wt(const float* __restrict__ W, ushort* __restrict__ Wt, int K){
  int idx = blockIdx.x*blockDim.x + threadIdx.x;
  if (idx >= K*HID) return;
  int k = idx >> 7, n = idx & 127;
  Wt[n*K + k] = f2bf(W[idx]);
}

// ---------------- bf16 MFMA GEMM: Out[M][128] = A[M][K] @ W[K][128] ----------------
// SLICED: write output in 4-slice layout: slice s (cols 32s..32s+31) stored as
// ushort[(s*N_NODES + row)*32 + (col&31)] — 64 B per row per slice.

template<int K, bool A_F32, bool OUT_BF16, bool BIAS, bool SCALE, bool SLICED>
__global__ __launch_bounds__(256) void k_gemm(const void* __restrict__ Aptr,
                                              const ushort* __restrict__ Wt,
                                              const float* __restrict__ bias,
                                              const float* __restrict__ rowscale,
                                              void* __restrict__ Outp, int M){
  __shared__ __align__(16) ushort lA[64*32];    // [row][k]
  __shared__ __align__(16) ushort lB[128*32];   // [n][k]
  int tid  = threadIdx.x;
  int wave = tid >> 6, lane = tid & 63;
  int kg   = lane >> 4, lr = lane & 15;
  int m0   = blockIdx.x * 64;

  f32x4 acc[8];
  #pragma unroll
  for (int i = 0; i < 8; i++) acc[i] = f32x4{0.f, 0.f, 0.f, 0.f};

  for (int k0 = 0; k0 < K; k0 += 32){
    if (A_F32){
      const float* A = (const float*)Aptr;
      #pragma unroll
      for (int i = 0; i < 2; i++){
        int l = tid + i*256;
        int r = l >> 3, c4 = (l & 7) * 4;
        int gm = m0 + r;
        float4 v = make_float4(0.f, 0.f, 0.f, 0.f);
        if (gm < M) v = *(const float4*)(A + (size_t)gm*K + k0 + c4);
        ushort4 u; u.x = f2bf(v.x); u.y = f2bf(v.y); u.z = f2bf(v.z); u.w = f2bf(v.w);
        *(ushort4*)&lA[r*32 + c4] = u;
      }
    } else {
      const ushort* A = (const ushort*)Aptr;
      int r = tid >> 2, c8 = (tid & 3) * 8;
      int gm = m0 + r;
      int4 v = make_int4(0, 0, 0, 0);
      if (gm < M) v = *(const int4*)(A + (size_t)gm*K + k0 + c8);
      *(int4*)&lA[r*32 + c8] = v;
    }
    #pragma unroll
    for (int i = 0; i < 2; i++){
      int l = tid + i*256;
      int n = l >> 2, c8 = (l & 3) * 8;
      *(int4*)&lB[n*32 + c8] = *(const int4*)(Wt + (size_t)n*K + k0 + c8);
    }
    __syncthreads();

    short8 a = *(const short8*)&lA[(wave*16 + lr)*32 + kg*8];
    #pragma unroll
    for (int nt = 0; nt < 8; nt++){
      short8 b = *(const short8*)&lB[(nt*16 + lr)*32 + kg*8];
      acc[nt] = __builtin_amdgcn_mfma_f32_16x16x32_bf16(a, b, acc[nt], 0, 0, 0);
    }
    __syncthreads();
  }

  #pragma unroll
  for (int nt = 0; nt < 8; nt++){
    #pragma unroll
    for (int r = 0; r < 4; r++){
      int gm = m0 + wave*16 + kg*4 + r;
      int n  = nt*16 + lr;
      if (gm < M){
        float v = acc[nt][r];
        if (BIAS)  v += bias[n];
        if (SCALE) v *= rowscale[gm];
        if (OUT_BF16){
          if (SLICED)
            ((ushort*)Outp)[((size_t)(n >> 5)*N_NODES + gm)*32 + (n & 31)] = f2bf(v);
          else
            ((ushort*)Outp)[(size_t)gm*HID + n] = f2bf(v);
        } else {
          ((float*)Outp)[(size_t)gm*HID + n] = v;
        }
      }
    }
  }
}

// ---------------- edge aggregation, L2-resident column slices ----------------
// hw sliced: hws[slice][node][16 uints] (32 bf16 cols, 64 B per row-slice;
// slice buffer = 3.2 MB -> fits one XCD's 4 MiB L2).
// slice = (blockIdx%8)&3 so each XCD (round-robin heuristic) touches one slice.
// Wave per (node, slice): 16-lane groups gather 4 edges per load instruction
// (SGPR base + 32-bit voffset), 16 edges in flight; butterfly-reduce groups.
// hw pre-scaled by dinv[row]. out[d] = dinv[d]*(sum_e hw[src_e] + hw[d]) + bias.

template<bool RELU, bool FUSE_POOL>
__global__ __launch_bounds__(256, 4) void k_aggs(const uint* __restrict__ hws,
                                                 const int* __restrict__ row_start,
                                                 const int* __restrict__ csr_src,
                                                 const float* __restrict__ dinv,
                                                 const float* __restrict__ bias,
                                                 uint* __restrict__ OutBf,
                                                 const int* __restrict__ batch,
                                                 const int* __restrict__ gstart,
                                                 float* __restrict__ g){
  int s8    = blockIdx.x & 7;
  int slice = s8 & 3;
  int chunk = (blockIdx.x >> 3)*2 + (s8 >> 2);   // [0, 12500)
  int wave  = threadIdx.x >> 6, lane = threadIdx.x & 63;
  int node  = chunk*4 + wave;
  int grp   = lane >> 4, li = lane & 15;
  const uint* __restrict__ sb = hws + (size_t)slice * (N_NODES*16u);

  uint ps = sb[((uint)node << 4) + li];          // self row (used by grp 0)
  float ax = (grp == 0) ? bf_lo(ps) : 0.f;
  float ay = (grp == 0) ? bf_hi(ps) : 0.f;

  int b = row_start[node], e = row_start[node+1];
  for (int j0 = b; j0 < e; j0 += 64){
    int jj = j0 + lane;
    int sl = (jj < e) ? csr_src[jj] : 0;
    int m = e - j0; if (m > 64) m = 64;
    for (int i = 0; i < m; i += 16){             // 16 edges in flight (4 loads)
      uint v[4]; float mk[4];
      #pragma unroll
      for (int j = 0; j < 4; j++){
        int idx = i + 4*j + grp;
        int s   = __shfl(sl, idx);               // bpermute
        bool ok = idx < m;
        mk[j] = ok ? 1.0f : 0.0f;
        uint off = ok ? (((uint)s << 4) + li) : (uint)li;  // row 0 safe
        v[j] = sb[off];
      }
      #pragma unroll
      for (int j = 0; j < 4; j++){
        ax += mk[j] * bf_lo(v[j]);
        ay += mk[j] * bf_hi(v[j]);
      }
    }
  }
  // reduce the 4 edge-groups
  ax += __shfl(ax, lane ^ 16); ay += __shfl(ay, lane ^ 16);
  ax += __shfl(ax, lane ^ 32); ay += __shfl(ay, lane ^ 32);

  if (grp == 0){
    float dd = dinv[node];
    int c0 = slice*32 + 2*li;
    float vx = ax*dd + bias[c0];
    float vy = ay*dd + bias[c0+1];
    if (RELU){ vx = fmaxf(vx, 0.f); vy = fmaxf(vy, 0.f); }
    if (FUSE_POOL){
      int bg = batch[node];
      float cnt = (float)(gstart[bg+1] - gstart[bg]);
      float sc = 1.0f / fmaxf(cnt, 1.0f);
      atomicAdd(&g[bg*HID + c0],     vx*sc);
      atomicAdd(&g[bg*HID + c0 + 1], vy*sc);
    } else {
      uint pk = (uint)f2bf(vx) | ((uint)f2bf(vy) << 16);
      OutBf[(size_t)node*64 + slice*16 + li] = pk;   // row-major bf16 h2
    }
  }
}

// ---------------- head ----------------

__global__ void k_ranges(const int* __restrict__ batch, int* __restrict__ gstart, int N, int G){
  int b = blockIdx.x*blockDim.x + threadIdx.x;
  if (b > G) return;
  int lo = 0, hi = N;
  while (lo < hi){ int mid = (lo + hi) >> 1; if (batch[mid] < b) lo = mid + 1; else hi = mid; }
  gstart[b] = lo;
}

__global__ void k_head(const float* __restrict__ g, const float* __restrict__ W1,
                       const float* __restrict__ b1, const float* __restrict__ W2,
                       const float* __restrict__ b2, float* __restrict__ out){
  __shared__ float row[128];
  __shared__ float z[128];
  int b = blockIdx.x, t = threadIdx.x;
  row[t] = g[b*HID + t];
  __syncthreads();
  float a = b1[t];
  #pragma unroll 8
  for (int k = 0; k < 128; k++) a += row[k] * W1[k*128 + t];
  z[t] = fmaxf(a, 0.f);
  __syncthreads();
  if (t < 3){
    float o = b2[t];
    #pragma unroll 8
    for (int k = 0; k < 128; k++) o += z[k] * W2[k*3 + t];
    out[b*3 + t] = o;
  }
}

// ---------------- launch ----------------

extern "C" void kernel_launch(void* const* d_in, const int* in_sizes, int n_in,
                              void* d_out, int out_size, void* d_ws, size_t ws_size,
                              hipStream_t stream) {
  const float* x     = (const float*)d_in[0];
  const int*   ei    = (const int*)  d_in[1];
  const int*   batch = (const int*)  d_in[2];
  const float* W_emb = (const float*)d_in[3];
  const float* b_emb = (const float*)d_in[4];
  const float* W_c1  = (const float*)d_in[5];
  const float* b_c1  = (const float*)d_in[6];
  const float* W_c2  = (const float*)d_in[7];
  const float* b_c2  = (const float*)d_in[8];
  const float* W_l1  = (const float*)d_in[9];
  const float* b_l1  = (const float*)d_in[10];
  const float* W_l2  = (const float*)d_in[11];
  const float* b_l2  = (const float*)d_in[12];
  const int* src = ei;
  const int* dst = ei + N_EDGES;
  float* out = (float*)d_out;

  char* ws = (char*)d_ws;
  size_t off = 0;
  auto alloc = [&](size_t n) -> char* {
    off = (off + 255) & ~(size_t)255;
    char* p = ws + off; off += n; return p;
  };
  int*    deg       = (int*)   alloc((size_t)N_NODES*4);
  int*    cursor    = (int*)   alloc((size_t)N_NODES*4);
  int*    row_start = (int*)   alloc((size_t)(N_NODES+1)*4);
  float*  dinv      = (float*) alloc((size_t)N_NODES*4);
  int*    lexc      = (int*)   alloc((size_t)N_NODES*4);
  int*    bsum      = (int*)   alloc((size_t)SCAN_NB*4);
  int*    boff      = (int*)   alloc((size_t)SCAN_NB*4);
  int*    csr_src   = (int*)   alloc((size_t)N_EDGES*4);
  ushort* wt_emb    = (ushort*)alloc((size_t)768*HID*2);
  ushort* wt_c1     = (ushort*)alloc((size_t)HID*HID*2);
  ushort* wt_c2     = (ushort*)alloc((size_t)HID*HID*2);
  ushort* t1        = (ushort*)alloc((size_t)N_NODES*HID*2);
  ushort* h2        = (ushort*)alloc((size_t)N_NODES*HID*2);
  uint*   hws       = (uint*)  alloc((size_t)N_NODES*64*4);   // 4 slices x [node][16 uints]
  float*  g         = (float*) alloc((size_t)N_GRAPHS*HID*4);
  int*    gstart    = (int*)   alloc((size_t)(N_GRAPHS+1)*4);

  hipMemsetAsync(deg,    0, (size_t)N_NODES*4, stream);
  hipMemsetAsync(cursor, 0, (size_t)N_NODES*4, stream);
  hipMemsetAsync(g,      0, (size_t)N_GRAPHS*HID*4, stream);

  int eb = (N_EDGES + 255) / 256;
  int nb = (N_NODES + 255) / 256;
  k_count  <<<eb, 256, 0, stream>>>(dst, deg, N_EDGES);
  k_dinv   <<<nb, 256, 0, stream>>>(deg, dinv, N_NODES);
  k_scan1  <<<SCAN_NB, SCAN_BS, 0, stream>>>(deg, lexc, bsum, N_NODES);
  k_scan2  <<<1, 256, 0, stream>>>(bsum, boff, row_start);
  k_scan3  <<<nb, 256, 0, stream>>>(lexc, boff, row_start, N_NODES);
  k_scatter<<<eb, 256, 0, stream>>>(src, dst, row_start, cursor, csr_src, N_EDGES);
  k_ranges <<<1, 256, 0, stream>>>(batch, gstart, N_NODES, N_GRAPHS);

  k_wt<<<(768*HID + 255)/256, 256, 0, stream>>>(W_emb, wt_emb, 768);
  k_wt<<<(HID*HID + 255)/256, 256, 0, stream>>>(W_c1,  wt_c1,  HID);
  k_wt<<<(HID*HID + 255)/256, 256, 0, stream>>>(W_c2,  wt_c2,  HID);

  int gemm_blocks = (N_NODES + 63) / 64;
  // t1 = x @ W_emb + b_emb (bf16, row-major)
  k_gemm<768, true,  true,  true,  false, false><<<gemm_blocks, 256, 0, stream>>>(x,  wt_emb, b_emb, nullptr, t1, N_NODES);
  // hws = (t1 @ W_c1) * dinv[row]  (bf16, SLICED)
  k_gemm<128, false, true,  false, true,  true ><<<gemm_blocks, 256, 0, stream>>>(t1, wt_c1, nullptr, dinv, hws, N_NODES);
  // h2 = relu(agg(hws) + b_c1) (bf16 row-major)
  k_aggs<true,  false><<<N_NODES, 256, 0, stream>>>(hws, row_start, csr_src, dinv, b_c1,
                                                    (uint*)h2, nullptr, nullptr, nullptr);
  // hws = (h2 @ W_c2) * dinv[row] (bf16, SLICED)
  k_gemm<128, false, true,  false, true,  true ><<<gemm_blocks, 256, 0, stream>>>(h2, wt_c2, nullptr, dinv, hws, N_NODES);
  // g += pooled(agg(hws) + b_c2)   (fused)
  k_aggs<false, true ><<<N_NODES, 256, 0, stream>>>(hws, row_start, csr_src, dinv, b_c2,
                                                    nullptr, batch, gstart, g);

  k_head<<<N_GRAPHS, 128, 0, stream>>>(g, W_l1, b_l1, W_l2, b_l2, out);
}

// Round 8
// 542.570 us; speedup vs baseline: 1.2159x; 1.2159x over previous
//
#include <hip/hip_runtime.h>
#include <hip/hip_bf16.h>

#define N_NODES  50000
#define N_GRAPHS 128
#define N_EDGES  800000
#define HID      128
#define SCAN_BS  256
#define SCAN_NB  ((N_NODES + SCAN_BS - 1) / SCAN_BS)

typedef __attribute__((ext_vector_type(8))) short short8;
typedef __attribute__((ext_vector_type(4))) float f32x4;

static __device__ __forceinline__ ushort f2bf(float f){
  __hip_bfloat16 h = __float2bfloat16(f);
  return *reinterpret_cast<ushort*>(&h);
}
static __device__ __forceinline__ float bf_lo(uint pk){ return __uint_as_float(pk << 16); }
static __device__ __forceinline__ float bf_hi(uint pk){ return __uint_as_float(pk & 0xffff0000u); }

// async 16B global->LDS (wave-uniform LDS base + lane*16)
static __device__ __forceinline__ void async16(const void* g, void* l){
  __builtin_amdgcn_global_load_lds(
      (const __attribute__((address_space(1))) void*)g,
      (__attribute__((address_space(3))) void*)l, 16, 0, 0);
}

// ---------------- graph preprocessing ----------------

__global__ void k_count(const int* __restrict__ dst, int* __restrict__ deg, int E){
  int i = blockIdx.x*blockDim.x + threadIdx.x;
  if (i < E) atomicAdd(&deg[dst[i]], 1);
}

// local scan + dinv fused
__global__ void k_scan1(const int* __restrict__ deg, int* __restrict__ lexc,
                        int* __restrict__ bsum, float* __restrict__ dinv, int N){
  __shared__ int s[SCAN_BS];
  int t = threadIdx.x, i = blockIdx.x*SCAN_BS + t;
  int v = (i < N) ? deg[i] : 0;
  if (i < N) dinv[i] = rsqrtf((float)(v + 1));   // +1 self loop
  s[t] = v;
  __syncthreads();
  int acc = v;
  for (int d = 1; d < SCAN_BS; d <<= 1){
    int u = (t >= d) ? s[t-d] : 0;
    __syncthreads();
    acc += u; s[t] = acc;
    __syncthreads();
  }
  if (i < N) lexc[i] = acc - v;
  if (t == SCAN_BS-1) bsum[blockIdx.x] = acc;
}

// block-sum scan + graph ranges fused (both tiny, independent inputs)
__global__ void k_scan2(const int* __restrict__ bsum, int* __restrict__ boff,
                        int* __restrict__ row_start,
                        const int* __restrict__ batch, int* __restrict__ gstart){
  __shared__ int s[SCAN_NB];
  int t = threadIdx.x;               // 256 threads, SCAN_NB <= 256
  int v = (t < SCAN_NB) ? bsum[t] : 0;
  if (t < SCAN_NB) s[t] = v;
  __syncthreads();
  int acc = v;
  for (int d = 1; d < SCAN_NB; d <<= 1){
    int u = (t >= d && t - d < SCAN_NB) ? s[t-d] : 0;
    __syncthreads();
    if (t < SCAN_NB){ acc += u; s[t] = acc; }
    __syncthreads();
  }
  if (t < SCAN_NB) boff[t] = acc - v;
  if (t == SCAN_NB-1) row_start[N_NODES] = acc;
  // graph ranges via binary search (t = 0..N_GRAPHS)
  if (t <= N_GRAPHS){
    int lo = 0, hi = N_NODES;
    while (lo < hi){ int mid = (lo + hi) >> 1; if (batch[mid] < t) lo = mid + 1; else hi = mid; }
    gstart[t] = lo;
  }
}

__global__ void k_scan3(const int* __restrict__ lexc, const int* __restrict__ boff,
                        int* __restrict__ row_start, int N){
  int i = blockIdx.x*blockDim.x + threadIdx.x;
  if (i < N) row_start[i] = lexc[i] + boff[i >> 8];
}

__global__ void k_scatter(const int* __restrict__ src, const int* __restrict__ dst,
                          const int* __restrict__ row_start, int* __restrict__ cursor,
                          int* __restrict__ csr_src, int E){
  int i = blockIdx.x*blockDim.x + threadIdx.x;
  if (i >= E) return;
  int d = dst[i];
  int pos = row_start[d] + atomicAdd(&cursor[d], 1);
  csr_src[pos] = src[i];
}

// all three weight transposes in one kernel: W[K][128] -> Wt[128][K] bf16
__global__ void k_wt_all(const float* __restrict__ W_emb, const float* __restrict__ W_c1,
                         const float* __restrict__ W_c2, ushort* __restrict__ wt_emb,
                         ushort* __restrict__ wt_c1, ushort* __restrict__ wt_c2){
  int idx = blockIdx.x*blockDim.x + threadIdx.x;
  const int T1 = 768*HID, T2 = HID*HID;
  if (idx < T1){
    int k = idx >> 7, n = idx & 127;
    wt_emb[n*768 + k] = f2bf(W_emb[idx]);
  } else if (idx < T1 + T2){
    int j = idx - T1, k = j >> 7, n = j & 127;
    wt_c1[n*HID + k] = f2bf(W_c1[j]);
  } else if (idx < T1 + 2*T2){
    int j = idx - T1 - T2, k = j >> 7, n = j & 127;
    wt_c2[n*HID + k] = f2bf(W_c2[j]);
  }
}

// ---------------- bf16 MFMA GEMM: Out[M][128] = A[M][K] @ W[K][128] ----------------
// A fragments loaded DIRECTLY from global per lane (each byte read once per block).
// B tile staged via async global_load_lds (width 16). No A-LDS, minimal VALU staging.

template<int K, bool A_F32, bool OUT_BF16, bool BIAS, bool SCALE>
__global__ __launch_bounds__(256) void k_gemm(const void* __restrict__ Aptr,
                                              const ushort* __restrict__ Wt,
                                              const float* __restrict__ bias,
                                              const float* __restrict__ rowscale,
                                              void* __restrict__ Outp, int M){
  __shared__ __align__(16) ushort lB[128*32];   // [n][k] 8 KB
  int tid  = threadIdx.x;
  int wave = tid >> 6, lane = tid & 63;
  int kg   = lane >> 4, lr = lane & 15;
  int m0   = blockIdx.x * 64;
  int gm   = m0 + wave*16 + lr;                 // A row this lane consumes
  bool arow_ok = gm < M;

  // async-stage addressing: instruction i of wave w covers B rows 32w+16i .. +15
  int brow_in_instr = lane >> 2;                // 0..15
  int belem        = (lane & 3) * 8;            // 0,8,16,24

  f32x4 acc[8];
  #pragma unroll
  for (int i = 0; i < 8; i++) acc[i] = f32x4{0.f, 0.f, 0.f, 0.f};

  for (int k0 = 0; k0 < K; k0 += 32){
    __syncthreads();   // all waves done reading lB from previous iteration
    #pragma unroll
    for (int i = 0; i < 2; i++){
      int r = wave*32 + i*16 + brow_in_instr;
      async16(Wt + (size_t)r*K + k0 + belem, &lB[(wave*32 + i*16)*32]);
    }

    // A fragment direct from global
    short8 a;
    if (A_F32){
      const float* A = (const float*)Aptr;
      float4 v0 = make_float4(0.f,0.f,0.f,0.f), v1 = v0;
      if (arow_ok){
        const float* p = A + (size_t)gm*K + k0 + kg*8;
        v0 = *(const float4*)p;
        v1 = *(const float4*)(p + 4);
      }
      union { short8 v; ushort u[8]; } ua;
      ua.u[0]=f2bf(v0.x); ua.u[1]=f2bf(v0.y); ua.u[2]=f2bf(v0.z); ua.u[3]=f2bf(v0.w);
      ua.u[4]=f2bf(v1.x); ua.u[5]=f2bf(v1.y); ua.u[6]=f2bf(v1.z); ua.u[7]=f2bf(v1.w);
      a = ua.v;
    } else {
      const ushort* A = (const ushort*)Aptr;
      union { int4 i4; short8 v; } ua;
      ua.i4 = make_int4(0,0,0,0);
      if (arow_ok) ua.i4 = *(const int4*)(A + (size_t)gm*K + k0 + kg*8);
      a = ua.v;
    }

    __syncthreads();   // drains async (vmcnt0) -> lB ready

    #pragma unroll
    for (int nt = 0; nt < 8; nt++){
      short8 b = *(const short8*)&lB[(nt*16 + lr)*32 + kg*8];
      acc[nt] = __builtin_amdgcn_mfma_f32_16x16x32_bf16(a, b, acc[nt], 0, 0, 0);
    }
  }

  #pragma unroll
  for (int nt = 0; nt < 8; nt++){
    #pragma unroll
    for (int r = 0; r < 4; r++){
      int gms = m0 + wave*16 + kg*4 + r;
      int n   = nt*16 + lr;
      if (gms < M){
        float v = acc[nt][r];
        if (BIAS)  v += bias[n];
        if (SCALE) v *= rowscale[gms];
        if (OUT_BF16) ((ushort*)Outp)[(size_t)gms*HID + n] = f2bf(v);
        else          ((float*)Outp)[(size_t)gms*HID + n] = v;
      }
    }
  }
}

// ---------------- edge aggregation (R6 structure, higher occupancy) ----------------
// One wave per node, full-wave row gather (64 lanes x uint = 256 B, 2 bf16 cols/lane).
// WAVE-UNIFORM __shfl index (readlane -> saddr loads), 16 gathers in flight,
// fully predicated tail. hw pre-scaled by dinv[row].
// out[d] = dinv[d]*(sum_e hw[src_e] + hw[d]) + bias
// FUSE_POOL: atomicAdd (row * 1/cnt) into g[batch] instead of writing the row.
// launch_bounds(256,8): VGPR fits <64, doubles resident waves vs (256,4).

template<bool RELU, bool FUSE_POOL>
__global__ __launch_bounds__(256, 8) void k_agg(const uint* __restrict__ hw,
                                                const int* __restrict__ row_start,
                                                const int* __restrict__ csr_src,
                                                const float* __restrict__ dinv,
                                                const float* __restrict__ bias,
                                                uint* __restrict__ OutBf,
                                                const int* __restrict__ batch,
                                                const int* __restrict__ gstart,
                                                float* __restrict__ g){
  int wave = threadIdx.x >> 6, lane = threadIdx.x & 63;
  int node = blockIdx.x*4 + wave;          // grid = 12500 blocks exactly
  uint pk0 = hw[(size_t)node*64 + lane];   // self loop (pre-scaled)
  float ax = bf_lo(pk0), ay = bf_hi(pk0);
  int b = row_start[node], e = row_start[node+1];
  for (int j0 = b; j0 < e; j0 += 64){
    int jj = j0 + lane;
    int sl = (jj < e) ? csr_src[jj] : 0;   // 0 is a safe row for masked slots
    int m = e - j0; if (m > 64) m = 64;
    for (int i = 0; i < m; i += 16){       // 16 gathers in flight
      uint v[16];
      #pragma unroll
      for (int j = 0; j < 16; j++){
        int s = __shfl(sl, i + j);         // uniform index -> readlane/saddr
        v[j] = hw[(size_t)s*64 + lane];
      }
      #pragma unroll
      for (int j = 0; j < 16; j++){
        float mk = (i + j < m) ? 1.0f : 0.0f;
        ax += mk * bf_lo(v[j]);
        ay += mk * bf_hi(v[j]);
      }
    }
  }
  float dd = dinv[node];
  float vx = ax*dd + bias[2*lane];
  float vy = ay*dd + bias[2*lane+1];
  if (RELU){ vx = fmaxf(vx, 0.f); vy = fmaxf(vy, 0.f); }
  if (FUSE_POOL){
    int bg = batch[node];
    float cnt = (float)(gstart[bg+1] - gstart[bg]);
    float sc = 1.0f / fmaxf(cnt, 1.0f);
    atomicAdd(&g[bg*HID + 2*lane],     vx*sc);
    atomicAdd(&g[bg*HID + 2*lane + 1], vy*sc);
  } else {
    uint pk = (uint)f2bf(vx) | ((uint)f2bf(vy) << 16);
    OutBf[(size_t)node*64 + lane] = pk;
  }
}

// ---------------- head ----------------

__global__ void k_head(const float* __restrict__ g, const float* __restrict__ W1,
                       const float* __restrict__ b1, const float* __restrict__ W2,
                       const float* __restrict__ b2, float* __restrict__ out){
  __shared__ float row[128];
  __shared__ float z[128];
  int b = blockIdx.x, t = threadIdx.x;
  row[t] = g[b*HID + t];
  __syncthreads();
  float a = b1[t];
  #pragma unroll 8
  for (int k = 0; k < 128; k++) a += row[k] * W1[k*128 + t];
  z[t] = fmaxf(a, 0.f);
  __syncthreads();
  if (t < 3){
    float o = b2[t];
    #pragma unroll 8
    for (int k = 0; k < 128; k++) o += z[k] * W2[k*3 + t];
    out[b*3 + t] = o;
  }
}

// ---------------- launch ----------------

extern "C" void kernel_launch(void* const* d_in, const int* in_sizes, int n_in,
                              void* d_out, int out_size, void* d_ws, size_t ws_size,
                              hipStream_t stream) {
  const float* x     = (const float*)d_in[0];
  const int*   ei    = (const int*)  d_in[1];
  const int*   batch = (const int*)  d_in[2];
  const float* W_emb = (const float*)d_in[3];
  const float* b_emb = (const float*)d_in[4];
  const float* W_c1  = (const float*)d_in[5];
  const float* b_c1  = (const float*)d_in[6];
  const float* W_c2  = (const float*)d_in[7];
  const float* b_c2  = (const float*)d_in[8];
  const float* W_l1  = (const float*)d_in[9];
  const float* b_l1  = (const float*)d_in[10];
  const float* W_l2  = (const float*)d_in[11];
  const float* b_l2  = (const float*)d_in[12];
  const int* src = ei;
  const int* dst = ei + N_EDGES;
  float* out = (float*)d_out;

  char* ws = (char*)d_ws;
  size_t off = 0;
  auto alloc = [&](size_t n) -> char* {
    off = (off + 255) & ~(size_t)255;
    char* p = ws + off; off += n; return p;
  };
  int*    deg       = (int*)   alloc((size_t)N_NODES*4);
  int*    cursor    = (int*)   alloc((size_t)N_NODES*4);   // adjacent to deg: one memset
  int*    row_start = (int*)   alloc((size_t)(N_NODES+1)*4);
  float*  dinv      = (float*) alloc((size_t)N_NODES*4);
  int*    lexc      = (int*)   alloc((size_t)N_NODES*4);
  int*    bsum      = (int*)   alloc((size_t)SCAN_NB*4);
  int*    boff      = (int*)   alloc((size_t)SCAN_NB*4);
  int*    csr_src   = (int*)   alloc((size_t)N_EDGES*4);
  ushort* wt_emb    = (ushort*)alloc((size_t)768*HID*2);
  ushort* wt_c1     = (ushort*)alloc((size_t)HID*HID*2);
  ushort* wt_c2     = (ushort*)alloc((size_t)HID*HID*2);
  ushort* t1        = (ushort*)alloc((size_t)N_NODES*HID*2);
  ushort* h2        = (ushort*)alloc((size_t)N_NODES*HID*2);
  uint*   hw        = (uint*)  alloc((size_t)N_NODES*64*4);   // packed bf16 x2
  float*  g         = (float*) alloc((size_t)N_GRAPHS*HID*4);
  int*    gstart    = (int*)   alloc((size_t)(N_GRAPHS+1)*4);

  // deg and cursor are adjacent in ws — zero both (plus alignment gap) in one call
  size_t dz = (size_t)((char*)csr_src - (char*)deg) - ((size_t)(N_NODES+1)*4 + 3*(size_t)N_NODES*4 + 2*(size_t)SCAN_NB*4 + 5*255);
  (void)dz;
  hipMemsetAsync(deg, 0, (size_t)((char*)row_start - (char*)deg), stream);  // covers deg+cursor
  hipMemsetAsync(g,   0, (size_t)N_GRAPHS*HID*4, stream);

  int eb = (N_EDGES + 255) / 256;
  int nb = (N_NODES + 255) / 256;
  k_count  <<<eb, 256, 0, stream>>>(dst, deg, N_EDGES);
  k_scan1  <<<SCAN_NB, SCAN_BS, 0, stream>>>(deg, lexc, bsum, dinv, N_NODES);
  k_scan2  <<<1, 256, 0, stream>>>(bsum, boff, row_start, batch, gstart);
  k_scan3  <<<nb, 256, 0, stream>>>(lexc, boff, row_start, N_NODES);
  k_scatter<<<eb, 256, 0, stream>>>(src, dst, row_start, cursor, csr_src, N_EDGES);
  k_wt_all <<<(768*HID + 2*HID*HID + 255)/256, 256, 0, stream>>>(W_emb, W_c1, W_c2,
                                                                 wt_emb, wt_c1, wt_c2);

  int gemm_blocks = (N_NODES + 63) / 64;
  // t1 = x @ W_emb + b_emb (bf16)
  k_gemm<768, true,  true,  true,  false><<<gemm_blocks, 256, 0, stream>>>(x,  wt_emb, b_emb, nullptr, t1, N_NODES);
  // hw = (t1 @ W_c1) * dinv[row]  (packed bf16)
  k_gemm<128, false, true,  false, true ><<<gemm_blocks, 256, 0, stream>>>(t1, wt_c1, nullptr, dinv, hw, N_NODES);
  // h2 = relu(agg(hw) + b_c1) (bf16)
  k_agg<true,  false><<<N_NODES/4, 256, 0, stream>>>(hw, row_start, csr_src, dinv, b_c1,
                                                     (uint*)h2, nullptr, nullptr, nullptr);
  // hw = (h2 @ W_c2) * dinv[row] (packed bf16)
  k_gemm<128, false, true,  false, true ><<<gemm_blocks, 256, 0, stream>>>(h2, wt_c2, nullptr, dinv, hw, N_NODES);
  // g += pooled(agg(hw) + b_c2)   (fused)
  k_agg<false, true ><<<N_NODES/4, 256, 0, stream>>>(hw, row_start, csr_src, dinv, b_c2,
                                                     nullptr, batch, gstart, g);

  k_head<<<N_GRAPHS, 128, 0, stream>>>(g, W_l1, b_l1, W_l2, b_l2, out);
}